// Round 5
// baseline (142.181 us; speedup 1.0000x reference)
//
#include <hip/hip_runtime.h>

#define IN_FEATURES 512
#define GRID_COLS   12   // grid_size + 2*order + 1 = 5 + 6 + 1
#define OUT_PER     8    // grid_size + order = 5 + 3

typedef float f32x4 __attribute__((ext_vector_type(4)));

// One thread per 16-byte output chunk (2 chunks per element).
// Normal (cached) stores: the rocclr fill kernel sustains 6.7 TB/s with
// normal stores on this chip; NT-store burst behavior is the suspect for
// the 4.1 TB/s plateau. 2x unroll issues both loads before both stores
// for extra memory-level parallelism.
__global__ __launch_bounds__(256) void bspline_basis_kernel(
    const float* __restrict__ x,
    const float* __restrict__ grid,
    f32x4* __restrict__ out4,
    int total_chunks)
{
    int tid    = blockIdx.x * blockDim.x + threadIdx.x;
    int stride = gridDim.x * blockDim.x;   // multiple of 1024 (blocks % 4 == 0)

    // feat invariant across grid-stride loop (stride/2 multiple of 512)
    int feat = (tid >> 1) & (IN_FEATURES - 1);
    const float* g = grid + feat * GRID_COLS;
    float g3    = g[3];          // first in-range knot (= -0.5)
    float h     = g[4] - g3;     // uniform spacing (= 0.4)
    float inv_h = 1.0f / h;

    int half = tid & 1;          // invariant too (stride even)
    int m0   = half << 2;

    int c = tid;
    for (; c + stride < total_chunks; c += 2 * stride) {
        int c1 = c + stride;
        float xv0 = x[c >> 1];
        float xv1 = x[c1 >> 1];

        f32x4 r0, r1;
        #pragma unroll
        for (int k = 0; k < 2; ++k) {
            float xv = k ? xv1 : xv0;
            float u  = (xv - g3) * inv_h;
            float fj = floorf(u);
            int jo = (int)fj;
            jo = jo < 0 ? 0 : (jo > 4 ? 4 : jo);
            float t = u - (float)jo;

            float omt  = 1.0f - t;
            float t2   = t * t;
            float t3   = t2 * t;
            float omt3 = omt * omt * omt;
            const float k6 = 1.0f / 6.0f;
            float b0 = omt3 * k6;
            float b1 = (3.0f * t3 - 6.0f * t2 + 4.0f) * k6;
            float b2 = (-3.0f * t3 + 3.0f * t2 + 3.0f * t + 1.0f) * k6;
            float b3 = t3 * k6;

            f32x4 r;
            #pragma unroll
            for (int q = 0; q < 4; ++q) {
                int s = (m0 + q) - jo;
                float val = 0.0f;
                val = (s == 0) ? b0 : val;
                val = (s == 1) ? b1 : val;
                val = (s == 2) ? b2 : val;
                val = (s == 3) ? b3 : val;
                r[q] = val;
            }
            if (k) r1 = r; else r0 = r;
        }

        out4[c]  = r0;
        out4[c1] = r1;
    }
    // tail (at most one iteration)
    for (; c < total_chunks; c += stride) {
        float xv = x[c >> 1];
        float u  = (xv - g3) * inv_h;
        float fj = floorf(u);
        int jo = (int)fj;
        jo = jo < 0 ? 0 : (jo > 4 ? 4 : jo);
        float t = u - (float)jo;

        float omt  = 1.0f - t;
        float t2   = t * t;
        float t3   = t2 * t;
        float omt3 = omt * omt * omt;
        const float k6 = 1.0f / 6.0f;
        float b0 = omt3 * k6;
        float b1 = (3.0f * t3 - 6.0f * t2 + 4.0f) * k6;
        float b2 = (-3.0f * t3 + 3.0f * t2 + 3.0f * t + 1.0f) * k6;
        float b3 = t3 * k6;

        f32x4 r;
        #pragma unroll
        for (int q = 0; q < 4; ++q) {
            int s = (m0 + q) - jo;
            float val = 0.0f;
            val = (s == 0) ? b0 : val;
            val = (s == 1) ? b1 : val;
            val = (s == 2) ? b2 : val;
            val = (s == 3) ? b3 : val;
            r[q] = val;
        }
        out4[c] = r;
    }
}

extern "C" void kernel_launch(void* const* d_in, const int* in_sizes, int n_in,
                              void* d_out, int out_size, void* d_ws, size_t ws_size,
                              hipStream_t stream) {
    const float* x    = (const float*)d_in[0];
    const float* grid = (const float*)d_in[1];
    f32x4* out4       = (f32x4*)d_out;

    int total_chunks = in_sizes[0] * 2;    // (N*IN) elements * 2 chunks each
    int threads = 256;
    int blocks = (total_chunks + threads - 1) / threads;
    if (blocks > 4096) blocks = 4096;      // grid-stride
    blocks = (blocks + 3) & ~3;            // keep stride a multiple of 1024

    bspline_basis_kernel<<<blocks, threads, 0, stream>>>(x, grid, out4, total_chunks);
}